// Round 4
// baseline (30.893 us; speedup 1.0000x reference)
//
#include <hip/hip_runtime.h>

// NuFACoef: out[b] = sum_{i,j} coef[i][j] * trace_ij / 16^(i+j+2),
// trace_ij = sum_k colsum(x^(i+2))[k]^(j+1); colsum chain u_{m+1} = u_m @ x.
//
// R4: streaming. Each wave owns 4 consecutive batches and processes them
// sequentially with register double-buffering (prefetch batch i+1's 16
// float4 loads, then compute batch i). Memory demand is continuous instead
// of the R1-R3 burst-then-compute-tail shape. Grid 512 blocks x 4 waves =
// 2048 waves; ~175 VGPR -> 2 waves/SIMD -> 2 blocks/CU fully resident.

#define NB 4   // batches per wave

__device__ __forceinline__ float4 xor_reduce_rg(float4 v) {
    v.x += __shfl_xor(v.x, 16, 64); v.y += __shfl_xor(v.y, 16, 64);
    v.z += __shfl_xor(v.z, 16, 64); v.w += __shfl_xor(v.w, 16, 64);
    v.x += __shfl_xor(v.x, 32, 64); v.y += __shfl_xor(v.y, 32, 64);
    v.z += __shfl_xor(v.z, 32, 64); v.w += __shfl_xor(v.w, 32, 64);
    return v;
}

__device__ __forceinline__ void load_batch(float4 dst[16], const float4* base) {
    #pragma unroll
    for (int k = 0; k < 16; ++k) dst[k] = base[16 * k];
}

__device__ __forceinline__ float compute_batch(const float4 xr[16],
                                               const float cs[4][4], int rg) {
    // u1 = colsum(x)
    float4 u = xr[0];
    #pragma unroll
    for (int k = 1; k < 16; ++k) {
        u.x += xr[k].x; u.y += xr[k].y; u.z += xr[k].z; u.w += xr[k].w;
    }
    u = xor_reduce_rg(u);

    float contrib = 0.f;
    #pragma unroll
    for (int m = 0; m < 4; ++m) {
        // u_new[c] = sum_i u[i]*x[i][c]; lane covers rows 16*rg..16*rg+15.
        // u[i] lives as component (i&3) on lane (i>>2); i = 16*rg + k.
        float4 acc = {0.f, 0.f, 0.f, 0.f};
        #pragma unroll
        for (int k = 0; k < 16; ++k) {
            const int src = 4 * rg + (k >> 2);
            const float uk = ((k & 3) == 0) ? __shfl(u.x, src, 64)
                           : ((k & 3) == 1) ? __shfl(u.y, src, 64)
                           : ((k & 3) == 2) ? __shfl(u.z, src, 64)
                           :                  __shfl(u.w, src, 64);
            acc.x += uk * xr[k].x; acc.y += uk * xr[k].y;
            acc.z += uk * xr[k].z; acc.w += uk * xr[k].w;
        }
        u = xor_reduce_rg(acc);   // colsum(x^(m+2)), duplicated across rgs

        #pragma unroll
        for (int c = 0; c < 4; ++c) {
            const float v1 = (c == 0) ? u.x : (c == 1) ? u.y : (c == 2) ? u.z : u.w;
            const float v2 = v1 * v1;
            const float v3 = v2 * v1;
            const float v4 = v2 * v2;
            contrib += cs[m][0] * v1 + cs[m][1] * v2 + cs[m][2] * v3 + cs[m][3] * v4;
        }
    }
    return contrib;   // identical across rgs; partial over this lane's 4 cols
}

__global__ __launch_bounds__(256) void nufa_kernel(
    const float* __restrict__ x, const float* __restrict__ coef,
    float* __restrict__ out, int B)
{
    const int wave = threadIdx.x >> 6;
    const int lane = threadIdx.x & 63;
    const int w    = blockIdx.x * 4 + wave;
    const int b0   = w * NB;               // this wave's batch chunk
    if (b0 >= B) return;

    const int rg = lane >> 4;
    const int cg = lane & 15;

    const float4* base = reinterpret_cast<const float4*>(x)
                         + (size_t)b0 * 1024 + 256 * rg + cg;

    // cs[i][j] = coef[i][j] / 16^(i+j+2) (uniform -> scalar path)
    float cs[4][4];
    #pragma unroll
    for (int i = 0; i < 4; ++i)
        #pragma unroll
        for (int j = 0; j < 4; ++j)
            cs[i][j] = coef[i * 4 + j] * (1.0f / (float)(1ull << (4 * (i + j + 2))));

    float4 bufA[16], bufB[16];
    load_batch(bufA, base);

    #pragma unroll
    for (int i = 0; i < NB; ++i) {
        // Prefetch batch i+1 into the idle buffer BEFORE computing batch i.
        // Compute's first use of the current buffer waits vmcnt(16), leaving
        // the 16 prefetch loads in flight under the compute.
        if (i + 1 < NB && b0 + i + 1 < B) {
            if (i & 1) load_batch(bufA, base + (size_t)(i + 1) * 1024);
            else       load_batch(bufB, base + (size_t)(i + 1) * 1024);
        }
        float c = (i & 1) ? compute_batch(bufB, cs, rg)
                          : compute_batch(bufA, cs, rg);
        #pragma unroll
        for (int d = 1; d < 16; d <<= 1) c += __shfl_xor(c, d, 64);
        if (lane == 0 && b0 + i < B) out[b0 + i] = c;
    }
}

extern "C" void kernel_launch(void* const* d_in, const int* in_sizes, int n_in,
                              void* d_out, int out_size, void* d_ws, size_t ws_size,
                              hipStream_t stream) {
    const float* x    = (const float*)d_in[0];
    const float* coef = (const float*)d_in[1];
    float* out        = (float*)d_out;
    const int B = in_sizes[0] / 4096;                  // 64*64 per batch
    const int waves  = (B + NB - 1) / NB;              // 1 wave per NB batches
    const int blocks = (waves + 3) / 4;                // 4 waves per block
    nufa_kernel<<<blocks, 256, 0, stream>>>(x, coef, out, B);
}

// Round 6
// 27.370 us; speedup vs baseline: 1.1287x; 1.1287x over previous
//
#include <hip/hip_runtime.h>

// NuFACoef: out[b] = sum_{i,j} coef[i][j] * trace_ij / 16^(i+j+2),
// trace_ij = sum_k colsum(x^(i+2))[k]^(j+1); colsum chain u_{m+1} = u_m @ x.
//
// R5b: attack the memory path. Loads are perfectly contiguous per wave
// (lane t reads f4[64i+t] -> 1KB/instr, 16KB linear) and nontemporal
// (bypass L2/L3 allocation; data is touched exactly once). Lane then owns
// rows 4i+rg (stride 4) x cols 4cg..4cg+3. The u-broadcast u[4i+rg]
// (component rg of lane i) goes through a per-wave LDS slot: 4 distinct
// addresses/instr, 16-lane same-address broadcast each -> conflict-free.

#define WPB 4   // waves per block

typedef float vf4 __attribute__((ext_vector_type(4)));   // native vector for
                                                         // __builtin_nontemporal_load

__device__ __forceinline__ vf4 xor_reduce_rg(vf4 v) {
    v.x += __shfl_xor(v.x, 16, 64); v.y += __shfl_xor(v.y, 16, 64);
    v.z += __shfl_xor(v.z, 16, 64); v.w += __shfl_xor(v.w, 16, 64);
    v.x += __shfl_xor(v.x, 32, 64); v.y += __shfl_xor(v.y, 32, 64);
    v.z += __shfl_xor(v.z, 32, 64); v.w += __shfl_xor(v.w, 32, 64);
    return v;
}

__global__ __launch_bounds__(256) void nufa_kernel(
    const float* __restrict__ x, const float* __restrict__ coef,
    float* __restrict__ out, int B)
{
    const int wave = threadIdx.x >> 6;
    const int lane = threadIdx.x & 63;
    const int b    = blockIdx.x * WPB + wave;
    if (b >= B) return;   // B = 8192 -> never taken (grid exact); kept for safety

    const int rg = lane >> 4;    // lane rows: 4i + rg, i = 0..15
    const int cg = lane & 15;    // cols 4cg..4cg+3

    __shared__ float us[WPB][4][64];   // per-wave u slots (steps 0..3)

    const vf4* xb = reinterpret_cast<const vf4*>(x) + (size_t)b * 1024;

    // Contiguous nontemporal stream: instr i covers f4[64i .. 64i+63] = 1KB.
    vf4 xr[16];
    #pragma unroll
    for (int i = 0; i < 16; ++i)
        xr[i] = __builtin_nontemporal_load(xb + 64 * i + lane);

    // cs[i][j] = coef[i][j] / 16^(i+j+2) (uniform -> scalar path)
    float cs[4][4];
    #pragma unroll
    for (int i = 0; i < 4; ++i)
        #pragma unroll
        for (int j = 0; j < 4; ++j)
            cs[i][j] = coef[i * 4 + j] * (1.0f / (float)(1ull << (4 * (i + j + 2))));

    // u1 = colsum(x): own-rows partial (rows 4i+rg), then reduce over rg.
    vf4 u = xr[0];
    #pragma unroll
    for (int i = 1; i < 16; ++i) u += xr[i];
    u = xor_reduce_rg(u);   // component c = colsum(col 4cg+c), all lanes

    // publish u1 to slot 0 (cols 4cg..4cg+3 from the rg==0 copy)
    if (rg == 0) *reinterpret_cast<vf4*>(&us[wave][0][4 * cg]) = u;

    float contrib = 0.f;
    #pragma unroll
    for (int m = 0; m < 4; ++m) {
        __syncthreads();   // slot m visible to all lanes of the wave
        // acc[c] = sum_i u[4i+rg] * x[4i+rg][c]
        const float* uslot = &us[wave][m][rg];
        vf4 acc = {0.f, 0.f, 0.f, 0.f};
        #pragma unroll
        for (int i = 0; i < 16; ++i) {
            const float uk = uslot[4 * i];   // 4 distinct addrs/wave: broadcast
            acc += uk * xr[i];
        }
        u = xor_reduce_rg(acc);   // colsum(x^(m+2))
        if (m < 3 && rg == 0)
            *reinterpret_cast<vf4*>(&us[wave][m + 1][4 * cg]) = u;

        // trace terms over this lane's 4 columns
        #pragma unroll
        for (int c = 0; c < 4; ++c) {
            const float v1 = (c == 0) ? u.x : (c == 1) ? u.y : (c == 2) ? u.z : u.w;
            const float v2 = v1 * v1;
            const float v3 = v2 * v1;
            const float v4 = v2 * v2;
            contrib += cs[m][0] * v1 + cs[m][1] * v2 + cs[m][2] * v3 + cs[m][3] * v4;
        }
    }

    // contrib depends only on cg: reduce the 16 cg lanes.
    #pragma unroll
    for (int d = 1; d < 16; d <<= 1) contrib += __shfl_xor(contrib, d, 64);
    if (lane == 0) out[b] = contrib;
}

extern "C" void kernel_launch(void* const* d_in, const int* in_sizes, int n_in,
                              void* d_out, int out_size, void* d_ws, size_t ws_size,
                              hipStream_t stream) {
    const float* x    = (const float*)d_in[0];
    const float* coef = (const float*)d_in[1];
    float* out        = (float*)d_out;
    const int B = in_sizes[0] / 4096;            // 64*64 per batch
    const int blocks = (B + WPB - 1) / WPB;      // 1 wave per batch
    nufa_kernel<<<blocks, 256, 0, stream>>>(x, coef, out, B);
}